// Round 2
// baseline (4740.099 us; speedup 1.0000x reference)
//
#include <hip/hip_runtime.h>

typedef __attribute__((ext_vector_type(4))) float f32x4;
typedef __attribute__((ext_vector_type(4))) unsigned int u32x4;
typedef unsigned char u8;
typedef unsigned int u32;

#define MBYTE (1024*1024)
#define TTOK 16384
#define HDIM 4096

__device__ __forceinline__ void gload_lds16(const void* g, void* l) {
  __builtin_amdgcn_global_load_lds((const __attribute__((address_space(1))) void*)g,
                                   (__attribute__((address_space(3))) void*)l, 16, 0, 0);
}

// ---- weight convert + transpose: W[k][n] f32 -> WT[n][k] fp8 (3 weights) ----
__global__ __launch_bounds__(256) void k_wconv(const float* __restrict__ w0,
                                               const float* __restrict__ w1,
                                               const float* __restrict__ w2,
                                               u8* __restrict__ out) {
  __shared__ float tl[64][68];   // stride 68 keeps 16B alignment, offsets banks by 4
  const int tid = threadIdx.x;
  const int bn = blockIdx.x, bk = blockIdx.y, z = blockIdx.z;
  const float* W = (z == 0) ? w0 : (z == 1 ? w1 : w2);
  u8* o = out + (size_t)z * 16 * MBYTE;
#pragma unroll
  for (int it = 0; it < 4; ++it) {
    int idx = it * 256 + tid;
    int r = idx >> 4, c4 = idx & 15;
    f32x4 v = *(const f32x4*)(W + (size_t)(bk * 64 + r) * HDIM + bn * 64 + c4 * 4);
    *(f32x4*)&tl[r][c4 * 4] = v;
  }
  __syncthreads();
  {
    // exactly 256 work items: n = tid>>2 (0..63), c = tid&3 (16 k-bytes each)
    int n = tid >> 2, c = tid & 3;
    u32 dw[4];
#pragma unroll
    for (int d = 0; d < 4; ++d) {
      int k0 = c * 16 + d * 4;
      int w = __builtin_amdgcn_cvt_pk_fp8_f32(tl[k0 + 0][n], tl[k0 + 1][n], 0, false);
      w = __builtin_amdgcn_cvt_pk_fp8_f32(tl[k0 + 2][n], tl[k0 + 3][n], w, true);
      dw[d] = (u32)w;
    }
    u32x4 pack = {dw[0], dw[1], dw[2], dw[3]};
    *(u32x4*)(o + (size_t)(bn * 64 + n) * HDIM + bk * 64 + c * 16) = pack;
  }
}

// ---- fused elementwise: MODE 0: relu+rms+quant (in=x); 1: add+rms+quant; 2: add+rms->yout ----
template <int MODE>
__global__ __launch_bounds__(256) void k_norm(const float* __restrict__ in,
                                              float* __restrict__ resid,
                                              const float* __restrict__ nw,
                                              u32* __restrict__ qout,
                                              float* __restrict__ asct,
                                              float* __restrict__ yout) {
  const int row = blockIdx.x, t = threadIdx.x;
  const size_t base = (size_t)row * HDIM;
  const f32x4* inr = (const f32x4*)(in + base);
  f32x4* residr = (f32x4*)(resid + base);
  f32x4 v[4];
  float ss = 0.f;
#pragma unroll
  for (int j = 0; j < 4; ++j) {
    f32x4 a = inr[j * 256 + t];
    if (MODE == 0) {
      a.x = fmaxf(a.x, 0.f); a.y = fmaxf(a.y, 0.f);
      a.z = fmaxf(a.z, 0.f); a.w = fmaxf(a.w, 0.f);
    } else {
      f32x4 rz = residr[j * 256 + t];
      a.x += rz.x; a.y += rz.y; a.z += rz.z; a.w += rz.w;
    }
    if (MODE < 2) residr[j * 256 + t] = a;
    v[j] = a;
    ss += a.x * a.x + a.y * a.y + a.z * a.z + a.w * a.w;
  }
#pragma unroll
  for (int m = 1; m <= 32; m <<= 1) ss += __shfl_xor(ss, m, 64);
  __shared__ float sred[4];
  if ((t & 63) == 0) sred[t >> 6] = ss;
  __syncthreads();
  float tot = sred[0] + sred[1] + sred[2] + sred[3];
  float rinv = rsqrtf(tot * (1.f / (float)HDIM) + 1e-6f);
#pragma unroll
  for (int j = 0; j < 4; ++j) {
    f32x4 nv = ((const f32x4*)nw)[j * 256 + t];
    f32x4 y;
    y.x = v[j].x * rinv * nv.x; y.y = v[j].y * rinv * nv.y;
    y.z = v[j].z * rinv * nv.z; y.w = v[j].w * rinv * nv.w;
    if (MODE == 2) {
      ((f32x4*)yout)[(size_t)row * 1024 + j * 256 + t] = y;
    } else {
      float am = fmaxf(fmaxf(fabsf(y.x), fabsf(y.y)), fmaxf(fabsf(y.z), fabsf(y.w)));
#pragma unroll
      for (int m = 1; m <= 16; m <<= 1) am = fmaxf(am, __shfl_xor(am, m, 64));
      am = fmaxf(am, 1e-12f);
      float scale = am / 448.f;
      float inv = 448.f / am;
      int d = __builtin_amdgcn_cvt_pk_fp8_f32(y.x * inv, y.y * inv, 0, false);
      d = __builtin_amdgcn_cvt_pk_fp8_f32(y.z * inv, y.w * inv, d, true);
      qout[(size_t)row * 1024 + j * 256 + t] = (u32)d;
      if ((t & 31) == 0) asct[(size_t)(j * 8 + (t >> 5)) * TTOK + row] = scale;
    }
  }
}

// ---- fp8 block-scaled GEMM: C[t][n] = sum_kb aS[kb][t]*bS[kb][nb] * sum_{k in kb} A[t][k]*B[n][k]
__global__ __launch_bounds__(256) void k_gemm(const u8* __restrict__ A,   // [T][4096] fp8
                                              const u8* __restrict__ B,   // [4096][4096] fp8 (row n, col k)
                                              const float* __restrict__ aS,  // [32][T]
                                              const float* __restrict__ bS,  // [32][32]
                                              float* __restrict__ C) {       // [T][4096]
  __shared__ u8 Al[128 * 32];
  __shared__ u8 Bl[128 * 32];
  const int tid = threadIdx.x;
  const int lane = tid & 63, wave = tid >> 6;
  const int bn = blockIdx.x, bm = blockIdx.y;
  const int brow = bm * 128, bcol = bn * 128;
  const int wr = (wave >> 1) * 64, wc = (wave & 1) * 64;
  const int r16 = lane & 15, q4 = lane >> 4;

  const u8* aP = A + (size_t)(brow + (tid >> 1)) * HDIM + (tid & 1) * 16;
  const u8* bP = B + (size_t)(bcol + (tid >> 1)) * HDIM + (tid & 1) * 16;
  u8* AlW = Al + wave * 1024;
  u8* BlW = Bl + wave * 1024;

  f32x4 accm[4][4] = {};
  f32x4 accb[4][4] = {};

#pragma unroll 1
  for (int kb = 0; kb < 32; ++kb) {
    const float wsb = bS[kb * 32 + bn];
    f32x4 sa[4];
#pragma unroll
    for (int m = 0; m < 4; ++m)
      sa[m] = *(const f32x4*)(aS + (size_t)kb * TTOK + brow + wr + m * 16 + q4 * 4);
#pragma unroll
    for (int ks = 0; ks < 4; ++ks) {
      const int kt = kb * 4 + ks;
      gload_lds16(aP + kt * 32, AlW);
      gload_lds16(bP + kt * 32, BlW);
      __syncthreads();
      long af[4], bf[4];
#pragma unroll
      for (int m = 0; m < 4; ++m)
        af[m] = *(const long*)(Al + (wr + m * 16 + r16) * 32 + q4 * 8);
#pragma unroll
      for (int n = 0; n < 4; ++n)
        bf[n] = *(const long*)(Bl + (wc + n * 16 + r16) * 32 + q4 * 8);
#pragma unroll
      for (int m = 0; m < 4; ++m)
#pragma unroll
        for (int n = 0; n < 4; ++n)
          accb[m][n] = __builtin_amdgcn_mfma_f32_16x16x32_fp8_fp8(af[m], bf[n], accb[m][n], 0, 0, 0);
      __syncthreads();
    }
#pragma unroll
    for (int m = 0; m < 4; ++m) {
      f32x4 s;
      s.x = sa[m].x * wsb; s.y = sa[m].y * wsb; s.z = sa[m].z * wsb; s.w = sa[m].w * wsb;
#pragma unroll
      for (int n = 0; n < 4; ++n) {
        accm[m][n].x += accb[m][n].x * s.x;
        accm[m][n].y += accb[m][n].y * s.y;
        accm[m][n].z += accb[m][n].z * s.z;
        accm[m][n].w += accb[m][n].w * s.w;
        accb[m][n] = (f32x4){0.f, 0.f, 0.f, 0.f};
      }
    }
  }
#pragma unroll
  for (int m = 0; m < 4; ++m) {
#pragma unroll
    for (int r = 0; r < 4; ++r) {
      float* Cp = C + (size_t)(brow + wr + m * 16 + q4 * 4 + r) * HDIM + bcol + wc + r16;
#pragma unroll
      for (int n = 0; n < 4; ++n) Cp[n * 16] = accm[m][n][r];
    }
  }
}

extern "C" void kernel_launch(void* const* d_in, const int* in_sizes, int n_in,
                              void* d_out, int out_size, void* d_ws, size_t ws_size,
                              hipStream_t stream) {
  const float* x  = (const float*)d_in[0];
  const float* nw = (const float*)d_in[1];
  const float* w0 = (const float*)d_in[2];
  const float* w1 = (const float*)d_in[3];
  const float* w2 = (const float*)d_in[4];
  const float* s0 = (const float*)d_in[5];
  const float* s1 = (const float*)d_in[6];
  const float* s2 = (const float*)d_in[7];
  float* out = (float*)d_out;
  char* ws = (char*)d_ws;

  u8*  wqt   = (u8*)ws;                               // 3 x 16MB
  u32* q     = (u32*)(ws + (size_t)48 * MBYTE);       // 64MB fp8 activations
  float* asc = (float*)(ws + (size_t)112 * MBYTE);    // 2MB  [32][T]
  float* rsd = (float*)(ws + (size_t)114 * MBYTE);    // 256MB residual

  k_wconv<<<dim3(64, 64, 3), 256, 0, stream>>>(w0, w1, w2, wqt);

  k_norm<0><<<TTOK, 256, 0, stream>>>(x, rsd, nw, q, asc, nullptr);
  k_gemm<<<dim3(32, 128), 256, 0, stream>>>((const u8*)q, wqt, asc, s0, out);

  k_norm<1><<<TTOK, 256, 0, stream>>>(out, rsd, nw + HDIM, q, asc, nullptr);
  k_gemm<<<dim3(32, 128), 256, 0, stream>>>((const u8*)q, wqt + (size_t)16 * MBYTE, asc, s1, out);

  k_norm<1><<<TTOK, 256, 0, stream>>>(out, rsd, nw + 2 * HDIM, q, asc, nullptr);
  k_gemm<<<dim3(32, 128), 256, 0, stream>>>((const u8*)q, wqt + (size_t)32 * MBYTE, asc, s2, out);

  k_norm<2><<<TTOK, 256, 0, stream>>>(out, rsd, nw + 3 * HDIM, nullptr, nullptr, out);
}

// Round 3
// 2120.797 us; speedup vs baseline: 2.2351x; 2.2351x over previous
//
#include <hip/hip_runtime.h>

typedef __attribute__((ext_vector_type(4))) float f32x4;
typedef __attribute__((ext_vector_type(4))) unsigned int u32x4;
typedef unsigned char u8;
typedef unsigned int u32;

#define MBYTE (1024*1024)
#define TTOK 16384
#define HDIM 4096

__device__ __forceinline__ void gload_lds16(const void* g, void* l) {
  __builtin_amdgcn_global_load_lds((const __attribute__((address_space(1))) void*)g,
                                   (__attribute__((address_space(3))) void*)l, 16, 0, 0);
}

// ---- weight convert + transpose: W[k][n] f32 -> WT[n][k] fp8 (3 weights) ----
__global__ __launch_bounds__(256) void k_wconv(const float* __restrict__ w0,
                                               const float* __restrict__ w1,
                                               const float* __restrict__ w2,
                                               u8* __restrict__ out) {
  __shared__ float tl[64][68];
  const int tid = threadIdx.x;
  const int bn = blockIdx.x, bk = blockIdx.y, z = blockIdx.z;
  const float* W = (z == 0) ? w0 : (z == 1 ? w1 : w2);
  u8* o = out + (size_t)z * 16 * MBYTE;
#pragma unroll
  for (int it = 0; it < 4; ++it) {
    int idx = it * 256 + tid;
    int r = idx >> 4, c4 = idx & 15;
    f32x4 v = *(const f32x4*)(W + (size_t)(bk * 64 + r) * HDIM + bn * 64 + c4 * 4);
    *(f32x4*)&tl[r][c4 * 4] = v;
  }
  __syncthreads();
  {
    int n = tid >> 2, c = tid & 3;
    u32 dw[4];
#pragma unroll
    for (int d = 0; d < 4; ++d) {
      int k0 = c * 16 + d * 4;
      int w = __builtin_amdgcn_cvt_pk_fp8_f32(tl[k0 + 0][n], tl[k0 + 1][n], 0, false);
      w = __builtin_amdgcn_cvt_pk_fp8_f32(tl[k0 + 2][n], tl[k0 + 3][n], w, true);
      dw[d] = (u32)w;
    }
    u32x4 pack = {dw[0], dw[1], dw[2], dw[3]};
    *(u32x4*)(o + (size_t)(bn * 64 + n) * HDIM + bk * 64 + c * 16) = pack;
  }
}

// ---- fused elementwise: MODE 0: relu+rms+quant; 1: add+rms+quant; 2: add+rms->yout ----
template <int MODE>
__global__ __launch_bounds__(256) void k_norm(const float* __restrict__ in,
                                              float* __restrict__ resid,
                                              const float* __restrict__ nw,
                                              u32* __restrict__ qout,
                                              float* __restrict__ asct,
                                              float* __restrict__ yout) {
  const int row = blockIdx.x, t = threadIdx.x;
  const size_t base = (size_t)row * HDIM;
  const f32x4* inr = (const f32x4*)(in + base);
  f32x4* residr = (f32x4*)(resid + base);
  f32x4 v[4];
  float ss = 0.f;
#pragma unroll
  for (int j = 0; j < 4; ++j) {
    f32x4 a = inr[j * 256 + t];
    if (MODE == 0) {
      a.x = fmaxf(a.x, 0.f); a.y = fmaxf(a.y, 0.f);
      a.z = fmaxf(a.z, 0.f); a.w = fmaxf(a.w, 0.f);
    } else {
      f32x4 rz = residr[j * 256 + t];
      a.x += rz.x; a.y += rz.y; a.z += rz.z; a.w += rz.w;
    }
    if (MODE < 2) residr[j * 256 + t] = a;
    v[j] = a;
    ss += a.x * a.x + a.y * a.y + a.z * a.z + a.w * a.w;
  }
#pragma unroll
  for (int m = 1; m <= 32; m <<= 1) ss += __shfl_xor(ss, m, 64);
  __shared__ float sred[4];
  if ((t & 63) == 0) sred[t >> 6] = ss;
  __syncthreads();
  float tot = sred[0] + sred[1] + sred[2] + sred[3];
  float rinv = rsqrtf(tot * (1.f / (float)HDIM) + 1e-6f);
#pragma unroll
  for (int j = 0; j < 4; ++j) {
    f32x4 nv = ((const f32x4*)nw)[j * 256 + t];
    f32x4 y;
    y.x = v[j].x * rinv * nv.x; y.y = v[j].y * rinv * nv.y;
    y.z = v[j].z * rinv * nv.z; y.w = v[j].w * rinv * nv.w;
    if (MODE == 2) {
      ((f32x4*)yout)[(size_t)row * 1024 + j * 256 + t] = y;
    } else {
      float am = fmaxf(fmaxf(fabsf(y.x), fabsf(y.y)), fmaxf(fabsf(y.z), fabsf(y.w)));
#pragma unroll
      for (int m = 1; m <= 16; m <<= 1) am = fmaxf(am, __shfl_xor(am, m, 64));
      am = fmaxf(am, 1e-12f);
      float scale = am / 448.f;
      float inv = 448.f / am;
      int d = __builtin_amdgcn_cvt_pk_fp8_f32(y.x * inv, y.y * inv, 0, false);
      d = __builtin_amdgcn_cvt_pk_fp8_f32(y.z * inv, y.w * inv, d, true);
      qout[(size_t)row * 1024 + j * 256 + t] = (u32)d;
      if ((t & 31) == 0) asct[(size_t)(j * 8 + (t >> 5)) * TTOK + row] = scale;
    }
  }
}

// ---- fp8 block-scaled GEMM, 128x128 tile, 8 waves (32x64 each), BK=128, dbuf LDS, T2 swizzle
__global__ __launch_bounds__(512, 4) void k_gemm(const u8* __restrict__ A,    // [T][4096] fp8
                                                 const u8* __restrict__ B,    // [4096][4096] fp8 (row n, col k)
                                                 const float* __restrict__ aS, // [32][T]
                                                 const float* __restrict__ bS, // [32][32]
                                                 float* __restrict__ C) {      // [T][4096]
  __shared__ u8 Al[2][128 * 128];
  __shared__ u8 Bl[2][128 * 128];
  const int tid = threadIdx.x;
  const int lane = tid & 63, wave = tid >> 6;
  // bijective XCD swizzle: 4096 blocks, 8 XCDs, 512 per chunk
  const int lin = blockIdx.x;
  const int swzb = (lin & 7) * 512 + (lin >> 3);
  const int bn = swzb & 31, bm = swzb >> 5;
  const int brow = bm * 128, bcol = bn * 128;
  const int wr = (wave >> 1) * 32, wc = (wave & 1) * 64;
  const int r16 = lane & 15, q4 = lane >> 4;
  const int swz = (r16 & 7) << 4;

  // staging: thread t covers rows srow and srow+64, 16 bytes each (inverse-swizzled source)
  const int srow = tid >> 3;
  const int scol = ((tid & 7) * 16) ^ ((srow & 7) << 4);
  const u8* aP = A + (size_t)(brow + srow) * HDIM + scol;
  const u8* bP = B + (size_t)(bcol + srow) * HDIM + scol;
  const int ldst = tid * 16;

  f32x4 accm[2][4] = {};
  f32x4 accb[2][4] = {};

#define STAGE(c, kt) do {                                        \
    const u8* a_ = aP + (kt) * 128;                              \
    const u8* b_ = bP + (kt) * 128;                              \
    gload_lds16(a_,                        &Al[c][ldst]);        \
    gload_lds16(a_ + (size_t)64 * HDIM,    &Al[c][ldst + 8192]); \
    gload_lds16(b_,                        &Bl[c][ldst]);        \
    gload_lds16(b_ + (size_t)64 * HDIM,    &Bl[c][ldst + 8192]); \
  } while (0)

  STAGE(0, 0);
  __syncthreads();

#pragma unroll 1
  for (int kt = 0; kt < 32; ++kt) {
    const int cur = kt & 1;
    if (kt < 31) STAGE(cur ^ 1, kt + 1);

    const float wsb = bS[kt * 32 + bn];
    const f32x4 sa0 = *(const f32x4*)(aS + (size_t)kt * TTOK + brow + wr + q4 * 4);
    const f32x4 sa1 = *(const f32x4*)(aS + (size_t)kt * TTOK + brow + wr + 16 + q4 * 4);

#pragma unroll
    for (int kk = 0; kk < 4; ++kk) {
      const int off = ((kk * 32) | (q4 * 8)) ^ swz;
      long af[2], bf[4];
      af[0] = *(const long*)(&Al[cur][(wr + r16) * 128 + off]);
      af[1] = *(const long*)(&Al[cur][(wr + 16 + r16) * 128 + off]);
#pragma unroll
      for (int n = 0; n < 4; ++n)
        bf[n] = *(const long*)(&Bl[cur][(wc + n * 16 + r16) * 128 + off]);
#pragma unroll
      for (int m = 0; m < 2; ++m)
#pragma unroll
        for (int n = 0; n < 4; ++n)
          accb[m][n] = __builtin_amdgcn_mfma_f32_16x16x32_fp8_fp8(af[m], bf[n], accb[m][n], 0, 0, 0);
    }

#pragma unroll
    for (int m = 0; m < 2; ++m) {
      const f32x4 sam = (m == 0) ? sa0 : sa1;
      f32x4 s;
      s.x = sam.x * wsb; s.y = sam.y * wsb; s.z = sam.z * wsb; s.w = sam.w * wsb;
#pragma unroll
      for (int n = 0; n < 4; ++n) {
        accm[m][n].x += accb[m][n].x * s.x;
        accm[m][n].y += accb[m][n].y * s.y;
        accm[m][n].z += accb[m][n].z * s.z;
        accm[m][n].w += accb[m][n].w * s.w;
        accb[m][n] = (f32x4){0.f, 0.f, 0.f, 0.f};
      }
    }
    __syncthreads();
  }
#undef STAGE

#pragma unroll
  for (int m = 0; m < 2; ++m) {
#pragma unroll
    for (int r = 0; r < 4; ++r) {
      float* Cp = C + (size_t)(brow + wr + m * 16 + q4 * 4 + r) * HDIM + bcol + wc + r16;
#pragma unroll
      for (int n = 0; n < 4; ++n) Cp[n * 16] = accm[m][n][r];
    }
  }
}

extern "C" void kernel_launch(void* const* d_in, const int* in_sizes, int n_in,
                              void* d_out, int out_size, void* d_ws, size_t ws_size,
                              hipStream_t stream) {
  const float* x  = (const float*)d_in[0];
  const float* nw = (const float*)d_in[1];
  const float* w0 = (const float*)d_in[2];
  const float* w1 = (const float*)d_in[3];
  const float* w2 = (const float*)d_in[4];
  const float* s0 = (const float*)d_in[5];
  const float* s1 = (const float*)d_in[6];
  const float* s2 = (const float*)d_in[7];
  float* out = (float*)d_out;
  char* ws = (char*)d_ws;

  u8*  wqt   = (u8*)ws;                               // 3 x 16MB
  u32* q     = (u32*)(ws + (size_t)48 * MBYTE);       // 64MB fp8 activations
  float* asc = (float*)(ws + (size_t)112 * MBYTE);    // 2MB  [32][T]
  float* rsd = (float*)(ws + (size_t)114 * MBYTE);    // 256MB residual

  k_wconv<<<dim3(64, 64, 3), 256, 0, stream>>>(w0, w1, w2, wqt);

  k_norm<0><<<TTOK, 256, 0, stream>>>(x, rsd, nw, q, asc, nullptr);
  k_gemm<<<4096, 512, 0, stream>>>((const u8*)q, wqt, asc, s0, out);

  k_norm<1><<<TTOK, 256, 0, stream>>>(out, rsd, nw + HDIM, q, asc, nullptr);
  k_gemm<<<4096, 512, 0, stream>>>((const u8*)q, wqt + (size_t)16 * MBYTE, asc, s1, out);

  k_norm<1><<<TTOK, 256, 0, stream>>>(out, rsd, nw + 2 * HDIM, q, asc, nullptr);
  k_gemm<<<4096, 512, 0, stream>>>((const u8*)q, wqt + (size_t)32 * MBYTE, asc, s2, out);

  k_norm<2><<<TTOK, 256, 0, stream>>>(out, rsd, nw + 3 * HDIM, nullptr, nullptr, out);
}

// Round 4
// 1952.071 us; speedup vs baseline: 2.4282x; 1.0864x over previous
//
#include <hip/hip_runtime.h>

typedef __attribute__((ext_vector_type(4))) float f32x4;
typedef __attribute__((ext_vector_type(4))) unsigned int u32x4;
typedef __attribute__((ext_vector_type(2))) long lg2;
typedef unsigned char u8;
typedef unsigned int u32;

#define MBYTE (1024*1024)
#define TTOK 16384
#define HDIM 4096

// Custom interleaved operand layout (both A and B, produced by our own kernels):
// row-major [4096B rows] of 32 K-tiles x 128B; within a tile, byte k (kk=k>>5,
// q4=(k>>3)&3, kkl=(k>>5)&1 of pair p=kk>>1, b=k&7) lives at p*64+q4*16+kkl*8+b.
// So ichunk j=p*4+q4 (16B) = lane(q4)'s fragment bytes for kk=2p and kk=2p+1.

__device__ __forceinline__ void gload_lds16(const void* g, void* l) {
  __builtin_amdgcn_global_load_lds((const __attribute__((address_space(1))) void*)g,
                                   (__attribute__((address_space(3))) void*)l, 16, 0, 0);
}

// ---- weight convert + transpose: W[k][n] f32 -> WT[n][k-interleaved] fp8 ----
__global__ __launch_bounds__(256) void k_wconv(const float* __restrict__ w0,
                                               const float* __restrict__ w1,
                                               const float* __restrict__ w2,
                                               u8* __restrict__ out) {
  __shared__ float tl[64][68];
  const int tid = threadIdx.x;
  const int bn = blockIdx.x, bk = blockIdx.y, z = blockIdx.z;
  const float* W = (z == 0) ? w0 : (z == 1 ? w1 : w2);
  u8* o = out + (size_t)z * 16 * MBYTE;
#pragma unroll
  for (int it = 0; it < 4; ++it) {
    int idx = it * 256 + tid;
    int r = idx >> 4, c4 = idx & 15;
    f32x4 v = *(const f32x4*)(W + (size_t)(bk * 64 + r) * HDIM + bn * 64 + c4 * 4);
    *(f32x4*)&tl[r][c4 * 4] = v;
  }
  __syncthreads();
  {
    // 256 items: n = tid>>2 (0..63), q4 = tid&3. 16B out = {kkl=0: klocal q4*8+0..7,
    // kkl=1: klocal 32+q4*8+0..7}; this bk covers pair-half p = bk&1 of tile bk>>1.
    int n = tid >> 2, q4 = tid & 3;
    u32 dw[4];
#pragma unroll
    for (int d = 0; d < 4; ++d) {
      int k0 = (d >> 1) * 32 + q4 * 8 + (d & 1) * 4;
      int w = __builtin_amdgcn_cvt_pk_fp8_f32(tl[k0 + 0][n], tl[k0 + 1][n], 0, false);
      w = __builtin_amdgcn_cvt_pk_fp8_f32(tl[k0 + 2][n], tl[k0 + 3][n], w, true);
      dw[d] = (u32)w;
    }
    u32x4 pack = {dw[0], dw[1], dw[2], dw[3]};
    *(u32x4*)(o + (size_t)(bn * 64 + n) * HDIM + (bk >> 1) * 128 + (bk & 1) * 64 + q4 * 16) = pack;
  }
}

// ---- fused elementwise: MODE 0: relu+rms+quant; 1: add+rms+quant; 2: add+rms->yout ----
template <int MODE>
__global__ __launch_bounds__(256) void k_norm(const float* __restrict__ in,
                                              float* __restrict__ resid,
                                              const float* __restrict__ nw,
                                              u32* __restrict__ qout,
                                              float* __restrict__ asct,
                                              float* __restrict__ yout) {
  const int row = blockIdx.x, t = threadIdx.x;
  const size_t base = (size_t)row * HDIM;
  const f32x4* inr = (const f32x4*)(in + base);
  f32x4* residr = (f32x4*)(resid + base);
  f32x4 v[4];
  float ss = 0.f;
#pragma unroll
  for (int j = 0; j < 4; ++j) {
    f32x4 a = inr[j * 256 + t];
    if (MODE == 0) {
      a.x = fmaxf(a.x, 0.f); a.y = fmaxf(a.y, 0.f);
      a.z = fmaxf(a.z, 0.f); a.w = fmaxf(a.w, 0.f);
    } else {
      f32x4 rz = residr[j * 256 + t];
      a.x += rz.x; a.y += rz.y; a.z += rz.z; a.w += rz.w;
    }
    if (MODE < 2) residr[j * 256 + t] = a;
    v[j] = a;
    ss += a.x * a.x + a.y * a.y + a.z * a.z + a.w * a.w;
  }
#pragma unroll
  for (int m = 1; m <= 32; m <<= 1) ss += __shfl_xor(ss, m, 64);
  __shared__ float sred[4];
  if ((t & 63) == 0) sred[t >> 6] = ss;
  __syncthreads();
  float tot = sred[0] + sred[1] + sred[2] + sred[3];
  float rinv = rsqrtf(tot * (1.f / (float)HDIM) + 1e-6f);
#pragma unroll
  for (int j = 0; j < 4; ++j) {
    f32x4 nv = ((const f32x4*)nw)[j * 256 + t];
    f32x4 y;
    y.x = v[j].x * rinv * nv.x; y.y = v[j].y * rinv * nv.y;
    y.z = v[j].z * rinv * nv.z; y.w = v[j].w * rinv * nv.w;
    if (MODE == 2) {
      ((f32x4*)yout)[(size_t)row * 1024 + j * 256 + t] = y;
    } else {
      float am = fmaxf(fmaxf(fabsf(y.x), fabsf(y.y)), fmaxf(fabsf(y.z), fabsf(y.w)));
#pragma unroll
      for (int m = 1; m <= 16; m <<= 1) am = fmaxf(am, __shfl_xor(am, m, 64));
      am = fmaxf(am, 1e-12f);
      float scale = am / 448.f;
      float inv = 448.f / am;
      int d = __builtin_amdgcn_cvt_pk_fp8_f32(y.x * inv, y.y * inv, 0, false);
      d = __builtin_amdgcn_cvt_pk_fp8_f32(y.z * inv, y.w * inv, d, true);
      // interleaved layout: permute u32 index within each 32-u32 (128B) K-tile
      int k4 = j * 256 + t;
      int k4w = k4 & 31;
      int k4n = (k4 & ~31) | (((k4w >> 4) & 1) << 4) | (((k4w >> 1) & 3) << 2)
              | (((k4w >> 3) & 1) << 1) | (k4w & 1);
      qout[(size_t)row * 1024 + k4n] = (u32)d;
      if ((t & 31) == 0) asct[(size_t)(j * 8 + (t >> 5)) * TTOK + row] = scale;
    }
  }
}

// ---- fp8 block-scaled GEMM, 128x128 tile, 8 waves (32x64 each), BK=128, dbuf, b128 reads
__global__ __launch_bounds__(512, 4) void k_gemm(const u8* __restrict__ A,    // [T][4096] fp8 interleaved
                                                 const u8* __restrict__ B,    // [4096][4096] fp8 interleaved
                                                 const float* __restrict__ aS, // [32][T]
                                                 const float* __restrict__ bS, // [32][32]
                                                 float* __restrict__ C) {      // [T][4096]
  __shared__ u8 Al[2][128 * 128];
  __shared__ u8 Bl[2][128 * 128];
  const int tid = threadIdx.x;
  const int lane = tid & 63, wave = tid >> 6;
  // bijective XCD swizzle: 4096 blocks, 8 XCDs, 512 per chunk
  const int lin = blockIdx.x;
  const int swzb = (lin & 7) * 512 + (lin >> 3);
  const int bn = swzb & 31, bm = swzb >> 5;
  const int brow = bm * 128, bcol = bn * 128;
  const int wr = (wave >> 1) * 32, wc = (wave & 1) * 64;
  const int r16 = lane & 15, q4 = lane >> 4;
  const int swz3 = r16 & 7;

  // staging: thread t covers rows srow and srow+64, 16B each; source chunk inverse-swizzled
  const int srow = tid >> 3;
  const int scol = (((tid & 7) ^ (srow & 7)) << 4);
  const u8* aP = A + (size_t)(brow + srow) * HDIM + scol;
  const u8* bP = B + (size_t)(bcol + srow) * HDIM + scol;
  const int ldst = tid * 16;

  f32x4 accm[2][4] = {};
  f32x4 accb[2][4];
  const f32x4 z4 = {0.f, 0.f, 0.f, 0.f};

#define STAGE(c, kt) do {                                        \
    const u8* a_ = aP + (kt) * 128;                              \
    const u8* b_ = bP + (kt) * 128;                              \
    gload_lds16(a_,                        &Al[c][ldst]);        \
    gload_lds16(a_ + (size_t)64 * HDIM,    &Al[c][ldst + 8192]); \
    gload_lds16(b_,                        &Bl[c][ldst]);        \
    gload_lds16(b_ + (size_t)64 * HDIM,    &Bl[c][ldst + 8192]); \
  } while (0)

  STAGE(0, 0);
  __syncthreads();

#pragma unroll 1
  for (int kt = 0; kt < 32; ++kt) {
    const int cur = kt & 1;
    if (kt < 31) STAGE(cur ^ 1, kt + 1);

    const float wsb = bS[kt * 32 + bn];
    const f32x4 sa0 = *(const f32x4*)(aS + (size_t)kt * TTOK + brow + wr + q4 * 4);
    const f32x4 sa1 = *(const f32x4*)(aS + (size_t)kt * TTOK + brow + wr + 16 + q4 * 4);

#pragma unroll
    for (int p = 0; p < 2; ++p) {
      const int coff = ((p * 4 + q4) ^ swz3) << 4;
      lg2 af[2], bf[4];
      af[0] = *(const lg2*)(&Al[cur][(wr + r16) * 128 + coff]);
      af[1] = *(const lg2*)(&Al[cur][(wr + 16 + r16) * 128 + coff]);
#pragma unroll
      for (int n = 0; n < 4; ++n)
        bf[n] = *(const lg2*)(&Bl[cur][(wc + n * 16 + r16) * 128 + coff]);
#pragma unroll
      for (int m = 0; m < 2; ++m)
#pragma unroll
        for (int n = 0; n < 4; ++n) {
          accb[m][n] = __builtin_amdgcn_mfma_f32_16x16x32_fp8_fp8(
              af[m].x, bf[n].x, (p == 0) ? z4 : accb[m][n], 0, 0, 0);
          accb[m][n] = __builtin_amdgcn_mfma_f32_16x16x32_fp8_fp8(
              af[m].y, bf[n].y, accb[m][n], 0, 0, 0);
        }
    }

#pragma unroll
    for (int m = 0; m < 2; ++m) {
      const f32x4 sam = (m == 0) ? sa0 : sa1;
      f32x4 s = sam * wsb;
#pragma unroll
      for (int n = 0; n < 4; ++n)
        accm[m][n] += accb[m][n] * s;
    }
    __syncthreads();
  }
#undef STAGE

#pragma unroll
  for (int m = 0; m < 2; ++m) {
#pragma unroll
    for (int r = 0; r < 4; ++r) {
      float* Cp = C + (size_t)(brow + wr + m * 16 + q4 * 4 + r) * HDIM + bcol + wc + r16;
#pragma unroll
      for (int n = 0; n < 4; ++n) Cp[n * 16] = accm[m][n][r];
    }
  }
}

extern "C" void kernel_launch(void* const* d_in, const int* in_sizes, int n_in,
                              void* d_out, int out_size, void* d_ws, size_t ws_size,
                              hipStream_t stream) {
  const float* x  = (const float*)d_in[0];
  const float* nw = (const float*)d_in[1];
  const float* w0 = (const float*)d_in[2];
  const float* w1 = (const float*)d_in[3];
  const float* w2 = (const float*)d_in[4];
  const float* s0 = (const float*)d_in[5];
  const float* s1 = (const float*)d_in[6];
  const float* s2 = (const float*)d_in[7];
  float* out = (float*)d_out;
  char* ws = (char*)d_ws;

  u8*  wqt   = (u8*)ws;                               // 3 x 16MB
  u32* q     = (u32*)(ws + (size_t)48 * MBYTE);       // 64MB fp8 activations
  float* asc = (float*)(ws + (size_t)112 * MBYTE);    // 2MB  [32][T]
  float* rsd = (float*)(ws + (size_t)114 * MBYTE);    // 256MB residual

  k_wconv<<<dim3(64, 64, 3), 256, 0, stream>>>(w0, w1, w2, wqt);

  k_norm<0><<<TTOK, 256, 0, stream>>>(x, rsd, nw, q, asc, nullptr);
  k_gemm<<<4096, 512, 0, stream>>>((const u8*)q, wqt, asc, s0, out);

  k_norm<1><<<TTOK, 256, 0, stream>>>(out, rsd, nw + HDIM, q, asc, nullptr);
  k_gemm<<<4096, 512, 0, stream>>>((const u8*)q, wqt + (size_t)16 * MBYTE, asc, s1, out);

  k_norm<1><<<TTOK, 256, 0, stream>>>(out, rsd, nw + 2 * HDIM, q, asc, nullptr);
  k_gemm<<<4096, 512, 0, stream>>>((const u8*)q, wqt + (size_t)32 * MBYTE, asc, s2, out);

  k_norm<2><<<TTOK, 256, 0, stream>>>(out, rsd, nw + 3 * HDIM, nullptr, nullptr, out);
}

// Round 5
// 1781.570 us; speedup vs baseline: 2.6606x; 1.0957x over previous
//
#include <hip/hip_runtime.h>

typedef __attribute__((ext_vector_type(4))) float f32x4;
typedef __attribute__((ext_vector_type(4))) unsigned int u32x4;
typedef __attribute__((ext_vector_type(4))) int i32x4;
typedef __attribute__((ext_vector_type(8))) int i32x8;
typedef unsigned char u8;
typedef unsigned int u32;

#define MBYTE (1024*1024)
#define TTOK 16384
#define HDIM 4096

// Custom interleaved operand layout (both A and B, produced by our own kernels):
// row-major [4096B rows] of 32 K-tiles x 128B; within a tile, byte k (kk=k>>5,
// q4=(k>>3)&3, kkl of pair p=kk>>1, b=k&7) lives at p*64+q4*16+kkl*8+b.
// K-permutation is applied identically to A and B, so any self-consistent
// HW fragment K-mapping yields the same dot product (scales fed as 1.0).

__device__ __forceinline__ void gload_lds16(const void* g, void* l) {
  __builtin_amdgcn_global_load_lds((const __attribute__((address_space(1))) void*)g,
                                   (__attribute__((address_space(3))) void*)l, 16, 0, 0);
}

// ---- weight convert + transpose: W[k][n] f32 -> WT[n][k-interleaved] fp8 ----
__global__ __launch_bounds__(256) void k_wconv(const float* __restrict__ w0,
                                               const float* __restrict__ w1,
                                               const float* __restrict__ w2,
                                               u8* __restrict__ out) {
  __shared__ float tl[64][68];
  const int tid = threadIdx.x;
  const int bn = blockIdx.x, bk = blockIdx.y, z = blockIdx.z;
  const float* W = (z == 0) ? w0 : (z == 1 ? w1 : w2);
  u8* o = out + (size_t)z * 16 * MBYTE;
#pragma unroll
  for (int it = 0; it < 4; ++it) {
    int idx = it * 256 + tid;
    int r = idx >> 4, c4 = idx & 15;
    f32x4 v = *(const f32x4*)(W + (size_t)(bk * 64 + r) * HDIM + bn * 64 + c4 * 4);
    *(f32x4*)&tl[r][c4 * 4] = v;
  }
  __syncthreads();
  {
    int n = tid >> 2, q4 = tid & 3;
    u32 dw[4];
#pragma unroll
    for (int d = 0; d < 4; ++d) {
      int k0 = (d >> 1) * 32 + q4 * 8 + (d & 1) * 4;
      int w = __builtin_amdgcn_cvt_pk_fp8_f32(tl[k0 + 0][n], tl[k0 + 1][n], 0, false);
      w = __builtin_amdgcn_cvt_pk_fp8_f32(tl[k0 + 2][n], tl[k0 + 3][n], w, true);
      dw[d] = (u32)w;
    }
    u32x4 pack = {dw[0], dw[1], dw[2], dw[3]};
    *(u32x4*)(o + (size_t)(bn * 64 + n) * HDIM + (bk >> 1) * 128 + (bk & 1) * 64 + q4 * 16) = pack;
  }
}

// ---- fused elementwise: MODE 0: relu+rms+quant; 1: add+rms+quant; 2: add+rms->yout ----
template <int MODE>
__global__ __launch_bounds__(256) void k_norm(const float* __restrict__ in,
                                              float* __restrict__ resid,
                                              const float* __restrict__ nw,
                                              u32* __restrict__ qout,
                                              float* __restrict__ asct,
                                              float* __restrict__ yout) {
  const int row = blockIdx.x, t = threadIdx.x;
  const size_t base = (size_t)row * HDIM;
  const f32x4* inr = (const f32x4*)(in + base);
  f32x4* residr = (f32x4*)(resid + base);
  f32x4 v[4];
  float ss = 0.f;
#pragma unroll
  for (int j = 0; j < 4; ++j) {
    f32x4 a = inr[j * 256 + t];
    if (MODE == 0) {
      a.x = fmaxf(a.x, 0.f); a.y = fmaxf(a.y, 0.f);
      a.z = fmaxf(a.z, 0.f); a.w = fmaxf(a.w, 0.f);
    } else {
      f32x4 rz = residr[j * 256 + t];
      a.x += rz.x; a.y += rz.y; a.z += rz.z; a.w += rz.w;
    }
    if (MODE < 2) residr[j * 256 + t] = a;
    v[j] = a;
    ss += a.x * a.x + a.y * a.y + a.z * a.z + a.w * a.w;
  }
#pragma unroll
  for (int m = 1; m <= 32; m <<= 1) ss += __shfl_xor(ss, m, 64);
  __shared__ float sred[4];
  if ((t & 63) == 0) sred[t >> 6] = ss;
  __syncthreads();
  float tot = sred[0] + sred[1] + sred[2] + sred[3];
  float rinv = rsqrtf(tot * (1.f / (float)HDIM) + 1e-6f);
#pragma unroll
  for (int j = 0; j < 4; ++j) {
    f32x4 nv = ((const f32x4*)nw)[j * 256 + t];
    f32x4 y;
    y.x = v[j].x * rinv * nv.x; y.y = v[j].y * rinv * nv.y;
    y.z = v[j].z * rinv * nv.z; y.w = v[j].w * rinv * nv.w;
    if (MODE == 2) {
      ((f32x4*)yout)[(size_t)row * 1024 + j * 256 + t] = y;
    } else {
      float am = fmaxf(fmaxf(fabsf(y.x), fabsf(y.y)), fmaxf(fabsf(y.z), fabsf(y.w)));
#pragma unroll
      for (int m = 1; m <= 16; m <<= 1) am = fmaxf(am, __shfl_xor(am, m, 64));
      am = fmaxf(am, 1e-12f);
      float scale = am / 448.f;
      float inv = 448.f / am;
      int d = __builtin_amdgcn_cvt_pk_fp8_f32(y.x * inv, y.y * inv, 0, false);
      d = __builtin_amdgcn_cvt_pk_fp8_f32(y.z * inv, y.w * inv, d, true);
      // interleaved layout: permute u32 index within each 32-u32 (128B) K-tile
      int k4 = j * 256 + t;
      int k4w = k4 & 31;
      int k4n = (k4 & ~31) | (((k4w >> 4) & 1) << 4) | (((k4w >> 1) & 3) << 2)
              | (((k4w >> 3) & 1) << 1) | (k4w & 1);
      qout[(size_t)row * 1024 + k4n] = (u32)d;
      if ((t & 31) == 0) asct[(size_t)(j * 8 + (t >> 5)) * TTOK + row] = scale;
    }
  }
}

// ---- fp8 block-scaled GEMM, 128x128 tile, 8 waves (32x64), BK=128, dbuf, MX-rate MFMA
__global__ __launch_bounds__(512, 4) void k_gemm(const u8* __restrict__ A,    // [T][4096] fp8 interleaved
                                                 const u8* __restrict__ B,    // [4096][4096] fp8 interleaved
                                                 const float* __restrict__ aS, // [32][T]
                                                 const float* __restrict__ bS, // [32][32]
                                                 float* __restrict__ C) {      // [T][4096]
  __shared__ u8 Al[2][128 * 128];
  __shared__ u8 Bl[2][128 * 128];
  const int tid = threadIdx.x;
  const int lane = tid & 63, wave = tid >> 6;
  // bijective XCD swizzle: 4096 blocks, 8 XCDs, 512 per chunk
  const int lin = blockIdx.x;
  const int swzb = (lin & 7) * 512 + (lin >> 3);
  const int bn = swzb & 31, bm = swzb >> 5;
  const int brow = bm * 128, bcol = bn * 128;
  const int wr = (wave >> 1) * 32, wc = (wave & 1) * 64;
  const int r16 = lane & 15, q4 = lane >> 4;
  const int swz3 = r16 & 7;

  // staging: thread t covers rows srow and srow+64, 16B each; source chunk inverse-swizzled
  const int srow = tid >> 3;
  const int scol = (((tid & 7) ^ (srow & 7)) << 4);
  const u8* aP = A + (size_t)(brow + srow) * HDIM + scol;
  const u8* bP = B + (size_t)(bcol + srow) * HDIM + scol;
  const int ldst = tid * 16;

  f32x4 accm[2][4] = {};
  const f32x4 z4 = {0.f, 0.f, 0.f, 0.f};
  const int c0 = (q4 ^ swz3) << 4;        // p=0 chunk for this lane
  const int c1 = ((4 + q4) ^ swz3) << 4;  // p=1 chunk

#define STAGE(c, kt) do {                                        \
    const u8* a_ = aP + (kt) * 128;                              \
    const u8* b_ = bP + (kt) * 128;                              \
    gload_lds16(a_,                        &Al[c][ldst]);        \
    gload_lds16(a_ + (size_t)64 * HDIM,    &Al[c][ldst + 8192]); \
    gload_lds16(b_,                        &Bl[c][ldst]);        \
    gload_lds16(b_ + (size_t)64 * HDIM,    &Bl[c][ldst + 8192]); \
  } while (0)

  STAGE(0, 0);
  __syncthreads();

#pragma unroll 1
  for (int kt = 0; kt < 32; ++kt) {
    const int cur = kt & 1;
    if (kt < 31) STAGE(cur ^ 1, kt + 1);

    const float wsb = bS[kt * 32 + bn];
    const f32x4 sa0 = *(const f32x4*)(aS + (size_t)kt * TTOK + brow + wr + q4 * 4);
    const f32x4 sa1 = *(const f32x4*)(aS + (size_t)kt * TTOK + brow + wr + 16 + q4 * 4);

    i32x8 afr[2], bfr[4];
#pragma unroll
    for (int m = 0; m < 2; ++m) {
      const u8* rp = &Al[cur][(wr + m * 16 + r16) * 128];
      i32x4 lo = *(const i32x4*)(rp + c0);
      i32x4 hi = *(const i32x4*)(rp + c1);
      afr[m] = __builtin_shufflevector(lo, hi, 0, 1, 2, 3, 4, 5, 6, 7);
    }
#pragma unroll
    for (int n = 0; n < 4; ++n) {
      const u8* rp = &Bl[cur][(wc + n * 16 + r16) * 128];
      i32x4 lo = *(const i32x4*)(rp + c0);
      i32x4 hi = *(const i32x4*)(rp + c1);
      bfr[n] = __builtin_shufflevector(lo, hi, 0, 1, 2, 3, 4, 5, 6, 7);
    }

#pragma unroll
    for (int m = 0; m < 2; ++m) {
      const f32x4 sam = (m == 0) ? sa0 : sa1;
      const f32x4 s = sam * wsb;
#pragma unroll
      for (int n = 0; n < 4; ++n) {
        f32x4 r = __builtin_amdgcn_mfma_scale_f32_16x16x128_f8f6f4(
            afr[m], bfr[n], z4, 0, 0, 0, 0x7F7F7F7F, 0, 0x7F7F7F7F);
        accm[m][n] += r * s;
      }
    }
    __syncthreads();
  }
#undef STAGE

#pragma unroll
  for (int m = 0; m < 2; ++m) {
#pragma unroll
    for (int r = 0; r < 4; ++r) {
      float* Cp = C + (size_t)(brow + wr + m * 16 + q4 * 4 + r) * HDIM + bcol + wc + r16;
#pragma unroll
      for (int n = 0; n < 4; ++n) Cp[n * 16] = accm[m][n][r];
    }
  }
}

extern "C" void kernel_launch(void* const* d_in, const int* in_sizes, int n_in,
                              void* d_out, int out_size, void* d_ws, size_t ws_size,
                              hipStream_t stream) {
  const float* x  = (const float*)d_in[0];
  const float* nw = (const float*)d_in[1];
  const float* w0 = (const float*)d_in[2];
  const float* w1 = (const float*)d_in[3];
  const float* w2 = (const float*)d_in[4];
  const float* s0 = (const float*)d_in[5];
  const float* s1 = (const float*)d_in[6];
  const float* s2 = (const float*)d_in[7];
  float* out = (float*)d_out;
  char* ws = (char*)d_ws;

  u8*  wqt   = (u8*)ws;                               // 3 x 16MB
  u32* q     = (u32*)(ws + (size_t)48 * MBYTE);       // 64MB fp8 activations
  float* asc = (float*)(ws + (size_t)112 * MBYTE);    // 2MB  [32][T]
  float* rsd = (float*)(ws + (size_t)114 * MBYTE);    // 256MB residual

  k_wconv<<<dim3(64, 64, 3), 256, 0, stream>>>(w0, w1, w2, wqt);

  k_norm<0><<<TTOK, 256, 0, stream>>>(x, rsd, nw, q, asc, nullptr);
  k_gemm<<<4096, 512, 0, stream>>>((const u8*)q, wqt, asc, s0, out);

  k_norm<1><<<TTOK, 256, 0, stream>>>(out, rsd, nw + HDIM, q, asc, nullptr);
  k_gemm<<<4096, 512, 0, stream>>>((const u8*)q, wqt + (size_t)16 * MBYTE, asc, s1, out);

  k_norm<1><<<TTOK, 256, 0, stream>>>(out, rsd, nw + 2 * HDIM, q, asc, nullptr);
  k_gemm<<<4096, 512, 0, stream>>>((const u8*)q, wqt + (size_t)32 * MBYTE, asc, s2, out);

  k_norm<2><<<TTOK, 256, 0, stream>>>(out, rsd, nw + 3 * HDIM, nullptr, nullptr, out);
}